// Round 8
// baseline (468.472 us; speedup 1.0000x reference)
//
#include <hip/hip_runtime.h>
#include <math.h>

#define NUM_LAYERS 3
#define KCB 2048        // codebook size
#define DIM 256         // embed dim
#define NROWS 32768     // B*T
#define NQ (NROWS * DIM)

// d_ws layout: F = fp16 codebook fragments (16x16x32 layout, verified).
//   per (layer,tn,kb): 1024 ushorts = [hi 512 | lo 512]; within a half:
//   lane*8 -> W[tn*16+(lane&15)][kb*32+(lane>>4)*8+j]. layer stride 1M ushorts.
//   wsq (fp32 ||w||^2, 3*2048) at byte offset F_BYTES.
// R8: NO LDS STAGING. Chunk working set = 32 KB = L1-sized; per-layer codebook
// 2 MB fits the per-XCD L2; all CUs walk the same chunks -> B-fragments are
// read directly global->VGPR (L1/L2-hit). Deletes 128 KB/chunk of ds_read +
// 32 KB DMA + the vmcnt-coupled barrier drains (Common-mistake #7).
#define F_BYTES (3u * 128u * 16384u)   // 6,291,456

// dynamic LDS partition (bytes) -- exchange + reductions only (35 KB)
#define XCH_OFF  0        // 2 bufs x [rg 0..3][kt 0..1] x 2048 B = 2 x 16384
#define BV_OFF   32768    // 8 waves x 32 rows f32 = 1024
#define BI_OFF   33792    // 8 x 32 i32 = 1024
#define BIDX_OFF 34816    // 128 i32 = 512
#define SMEM_BYTES 35328

typedef _Float16 half8 __attribute__((ext_vector_type(8)));
typedef float   f32x4 __attribute__((ext_vector_type(4)));

// ---------------- prep: ||w||^2 (unchanged, verified) ----------------
__global__ void rvq_wsq(const float* __restrict__ cb, float* __restrict__ wsq)
{
    int tid = blockIdx.x * 256 + threadIdx.x;   // 0 .. 6143
    const float* p = cb + (size_t)tid * DIM;
    float s = 0.f;
    #pragma unroll
    for (int u = 0; u < 64; ++u) {
        float4 v = *(const float4*)(p + u * 4);
        s = fmaf(v.x, v.x, s); s = fmaf(v.y, v.y, s);
        s = fmaf(v.z, v.z, s); s = fmaf(v.w, v.w, s);
    }
    wsq[tid] = s;
}

// ---------------- prep: fp16 hi/lo fragment repack (unchanged, verified) ----------------
__global__ void rvq_repack(const float* __restrict__ cb, unsigned short* __restrict__ F)
{
    int b = blockIdx.x;           // layer*1024 + tn*8 + kb
    int layer = b >> 10;
    int rem   = b & 1023;
    int tn    = rem >> 3;
    int kb    = rem & 7;
    int lane  = threadIdx.x;

    int cw = tn * 16 + (lane & 15);
    int k0 = kb * 32 + (lane >> 4) * 8;
    const float* src = cb + ((size_t)(layer * KCB + cw)) * DIM + k0;
    float4 x0 = *(const float4*)(src);
    float4 x1 = *(const float4*)(src + 4);
    float v[8] = {x0.x, x0.y, x0.z, x0.w, x1.x, x1.y, x1.z, x1.w};

    half8 hi, lo;
    #pragma unroll
    for (int j = 0; j < 8; ++j) {
        _Float16 h = (_Float16)v[j];
        hi[j] = h;
        lo[j] = (_Float16)(v[j] - (float)h);
    }
    size_t base = ((size_t)b) * 1024;   // ushort units (2048 B per (layer,tn,kb))
    *(half8*)(F + base + lane * 8)        = hi;
    *(half8*)(F + base + 512 + lane * 8)  = lo;
}

// ---------------- direct-global cross: 16-cw tile over this wave's k-half ----------------
// B-fragments streamed global->VGPR, 2-kb-deep (8 loads in flight at the top;
// compiler inserts staged vmcnt waits). p already includes kt*4096 + lane*8.
// R0-proven accumulator mapping; literal unrolled indices only (rule #20).
__device__ __forceinline__ void tile_direct(
    const unsigned short* __restrict__ p,
    const half8 (&ahi)[2][4], const half8 (&alo)[2][4],
    f32x4 (&po)[2])
{
    const f32x4 z = {0.f, 0.f, 0.f, 0.f};
    f32x4 a00 = z, a01 = z, a10 = z, a11 = z;
    half8 bh[4], bl[4];
    bh[0] = *(const half8*)(p);        bl[0] = *(const half8*)(p + 512);
    bh[1] = *(const half8*)(p + 1024); bl[1] = *(const half8*)(p + 1536);
    #pragma unroll
    for (int kq = 0; kq < 4; ++kq) {
        if (kq < 2) {
            bh[kq + 2] = *(const half8*)(p + (kq + 2) * 1024);
            bl[kq + 2] = *(const half8*)(p + (kq + 2) * 1024 + 512);
        }
        if (kq & 1) {
            a01 = __builtin_amdgcn_mfma_f32_16x16x32_f16(ahi[0][kq], bh[kq], a01, 0, 0, 0);
            a11 = __builtin_amdgcn_mfma_f32_16x16x32_f16(ahi[1][kq], bh[kq], a11, 0, 0, 0);
            a01 = __builtin_amdgcn_mfma_f32_16x16x32_f16(alo[0][kq], bh[kq], a01, 0, 0, 0);
            a11 = __builtin_amdgcn_mfma_f32_16x16x32_f16(alo[1][kq], bh[kq], a11, 0, 0, 0);
            a01 = __builtin_amdgcn_mfma_f32_16x16x32_f16(ahi[0][kq], bl[kq], a01, 0, 0, 0);
            a11 = __builtin_amdgcn_mfma_f32_16x16x32_f16(ahi[1][kq], bl[kq], a11, 0, 0, 0);
        } else {
            a00 = __builtin_amdgcn_mfma_f32_16x16x32_f16(ahi[0][kq], bh[kq], a00, 0, 0, 0);
            a10 = __builtin_amdgcn_mfma_f32_16x16x32_f16(ahi[1][kq], bh[kq], a10, 0, 0, 0);
            a00 = __builtin_amdgcn_mfma_f32_16x16x32_f16(alo[0][kq], bh[kq], a00, 0, 0, 0);
            a10 = __builtin_amdgcn_mfma_f32_16x16x32_f16(alo[1][kq], bh[kq], a10, 0, 0, 0);
            a00 = __builtin_amdgcn_mfma_f32_16x16x32_f16(ahi[0][kq], bl[kq], a00, 0, 0, 0);
            a10 = __builtin_amdgcn_mfma_f32_16x16x32_f16(ahi[1][kq], bl[kq], a10, 0, 0, 0);
        }
    }
    #pragma unroll
    for (int i = 0; i < 4; ++i) { po[0][i] = a00[i] + a01[i]; po[1][i] = a10[i] + a11[i]; }
}

// ---------------- main fused RVQ ----------------
// 512 thr = 8 waves: wave = rg(0..3)*2 + kt(0..1). 128 rows/block, grid 256.
// k-half fragments (64 VGPRs, proven no-spill; toolchain pins 512-thr kernels
// at 128 VGPR, so live set kept ~<=130). No LDS staging: B streamed from
// global (L1/L2-hit). Double-buffered Xch -> ONE lgkm-only barrier per chunk
// (write Xch[c&1] -> barrier -> read Xch[c&1]; WAR across chunks is safe via
// the barrier rendezvous). rsq dropped (argmin-invariant); wq prefetched.
__global__ __launch_bounds__(512, 2)
void rvq_main(const float* __restrict__ h,
              const float* __restrict__ cb,
              const unsigned short* __restrict__ F,
              const float* __restrict__ wsq,
              float* __restrict__ out)
{
    extern __shared__ char smem[];
    char*  Xch     = smem + XCH_OFF;
    float* bV_sh   = (float*)(smem + BV_OFF);
    int*   bI_sh   = (int*)  (smem + BI_OFF);
    int*   bidx_sh = (int*)  (smem + BIDX_OFF);

    const int t     = threadIdx.x;
    const int lane  = t & 63;
    const int wv    = t >> 6;         // 0..7
    const int kt    = wv & 1;         // k-team: k in [kt*128, kt*128+128)
    const int rg    = wv >> 1;        // row group (32 rows each)
    const int rowB  = blockIdx.x * 128;
    const int row0w = rowB + rg * 32;
    const int arow  = lane & 15;      // A row / C col
    const int aq    = lane >> 4;      // k-quad / C row-quad

    // ---- residual fragments (fp16 hi/lo, k-half only) ----
    half8 ahi[2][4], alo[2][4];
    #pragma unroll
    for (int mi = 0; mi < 2; ++mi) {
        #pragma unroll
        for (int kq = 0; kq < 4; ++kq) {
            const float* p = h + (size_t)(row0w + mi * 16 + arow) * DIM + (kt * 4 + kq) * 32 + aq * 8;
            float4 x0 = *(const float4*)(p);
            float4 x1 = *(const float4*)(p + 4);
            float v[8] = {x0.x, x0.y, x0.z, x0.w, x1.x, x1.y, x1.z, x1.w};
            #pragma unroll
            for (int j = 0; j < 8; ++j) {
                _Float16 hv = (_Float16)v[j];
                ahi[mi][kq][j] = hv;
                alo[mi][kq][j] = (_Float16)(v[j] - (float)hv);
            }
        }
    }

    for (int l = 0; l < NUM_LAYERS; ++l) {
        const float* __restrict__ Wl  = cb + (size_t)l * KCB * DIM;
        const float* __restrict__ wql = wsq + l * KCB;
        // layer base in ushort units + this wave's k-half + lane offset
        const unsigned short* Fl = F + (size_t)l * 1048576 + kt * 4096 + lane * 8;

        float bestV[2][4];
        int   bestI[2][4];
        #pragma unroll
        for (int mi = 0; mi < 2; ++mi)
            #pragma unroll
            for (int i = 0; i < 4; ++i) { bestV[mi][i] = INFINITY; bestI[mi][i] = 0; }

        float wq_cur = wql[kt * 16 + arow];

        // ---- 64 chunks of 32 cw; ONE lgkm-only barrier per chunk ----
        for (int c = 0; c < 64; ++c) {
            const int cur = c & 1;
            float wq_next = (c < 63) ? wql[(c + 1) * 32 + kt * 16 + arow] : 0.f;
            const unsigned short* Ftile = Fl + (size_t)c * 16384;

            // non-owned tile (ti = 1-kt): partials -> Xch[cur]
            {
                f32x4 pn[2];
                tile_direct(Ftile + (size_t)(1 - kt) * 8192, ahi, alo, pn);
                char* xw = Xch + (size_t)cur * 16384 + rg * 4096 + kt * 2048;
                *(f32x4*)(xw + lane * 16)        = pn[0];
                *(f32x4*)(xw + 1024 + lane * 16) = pn[1];
            }
            // owned tile (ti = kt): keep partials in regs
            f32x4 po[2];
            tile_direct(Ftile + (size_t)kt * 8192, ahi, alo, po);

            // barrier: Xch writes visible (lgkm only -- global B-loads may
            // stay in flight; they land in private VGPRs).
            asm volatile("s_waitcnt lgkmcnt(0)" ::: "memory");
            __builtin_amdgcn_sched_barrier(0);
            __builtin_amdgcn_s_barrier();
            __builtin_amdgcn_sched_barrier(0);

            const char* xr = Xch + (size_t)cur * 16384 + rg * 4096 + (1 - kt) * 2048;
            f32x4 pp0 = *(const f32x4*)(xr + lane * 16);
            f32x4 pp1 = *(const f32x4*)(xr + 1024 + lane * 16);

            const int col = c * 32 + kt * 16 + arow;
            #pragma unroll
            for (int i = 0; i < 4; ++i) {
                float d0 = fmaf(-2.f, po[0][i] + pp0[i], wq_cur);
                if (d0 < bestV[0][i]) { bestV[0][i] = d0; bestI[0][i] = col; }
                float d1 = fmaf(-2.f, po[1][i] + pp1[i], wq_cur);
                if (d1 < bestV[1][i]) { bestV[1][i] = d1; bestI[1][i] = col; }
            }
            wq_cur = wq_next;
            // no second barrier: chunk c+1 writes Xch[1-cur]; a chunk-(c+2)
            // write of Xch[cur] is ordered after every wave's chunk-c read by
            // the chunk-(c+1) barrier rendezvous.
        }

        // ---- argmin: reduce across the 16 arow-lanes sharing each row-quad ----
        #pragma unroll
        for (int mi = 0; mi < 2; ++mi)
            #pragma unroll
            for (int i = 0; i < 4; ++i) {
                float bv = bestV[mi][i]; int bi = bestI[mi][i];
                #pragma unroll
                for (int s = 8; s; s >>= 1) {
                    float ov = __shfl_xor(bv, s, 16);
                    int   oi = __shfl_xor(bi, s, 16);
                    if (ov < bv || (ov == bv && oi < bi)) { bv = ov; bi = oi; }
                }
                bestV[mi][i] = bv; bestI[mi][i] = bi;
            }
        if (arow == 0) {
            #pragma unroll
            for (int mi = 0; mi < 2; ++mi)
                #pragma unroll
                for (int i = 0; i < 4; ++i) {
                    bV_sh[wv * 32 + mi * 16 + aq * 4 + i] = bestV[mi][i];
                    bI_sh[wv * 32 + mi * 16 + aq * 4 + i] = bestI[mi][i];
                }
        }
        __syncthreads();

        // ---- combine the two k-teams' col-halves per row, write index ----
        if (t < 128) {
            int rgi = t >> 5, rl = t & 31;
            float v0 = bV_sh[(rgi * 2 + 0) * 32 + rl]; int i0 = bI_sh[(rgi * 2 + 0) * 32 + rl];
            float v1 = bV_sh[(rgi * 2 + 1) * 32 + rl]; int i1 = bI_sh[(rgi * 2 + 1) * 32 + rl];
            int bi = (v1 < v0 || (v1 == v0 && i1 < i0)) ? i1 : i0;
            bidx_sh[t] = bi;
            out[NQ + (size_t)l * NROWS + rowB + t] = (float)bi;
        }
        __syncthreads();   // bidx_sh visible

        if (l < NUM_LAYERS - 1) {
            // ---- residual update in registers: r <- (hi+lo) - w, re-split ----
            #pragma unroll
            for (int mi = 0; mi < 2; ++mi) {
                const int bi = bidx_sh[rg * 32 + mi * 16 + arow];
                const float* wrow = Wl + (size_t)bi * DIM;
                #pragma unroll
                for (int kq = 0; kq < 4; ++kq) {
                    const float* wp = wrow + (kt * 4 + kq) * 32 + aq * 8;
                    float4 w0 = *(const float4*)(wp);
                    float4 w1 = *(const float4*)(wp + 4);
                    float wv8[8] = {w0.x, w0.y, w0.z, w0.w, w1.x, w1.y, w1.z, w1.w};
                    #pragma unroll
                    for (int j = 0; j < 8; ++j) {
                        float r = ((float)ahi[mi][kq][j] + (float)alo[mi][kq][j]) - wv8[j];
                        _Float16 hv = (_Float16)r;
                        ahi[mi][kq][j] = hv;
                        alo[mi][kq][j] = (_Float16)(r - (float)hv);
                    }
                }
            }
        } else {
            // ---- final: out = h - (r2 - w3); each lane covers its k-half ----
            #pragma unroll
            for (int mi = 0; mi < 2; ++mi) {
                const int row = row0w + mi * 16 + arow;
                const int bi  = bidx_sh[rg * 32 + mi * 16 + arow];
                const float* wrow = Wl + (size_t)bi * DIM;
                #pragma unroll
                for (int kq = 0; kq < 4; ++kq) {
                    const int ko = (kt * 4 + kq) * 32 + aq * 8;
                    const float* wp = wrow + ko;
                    const float* hp = h + (size_t)row * DIM + ko;
                    float4 w0 = *(const float4*)(wp);
                    float4 w1 = *(const float4*)(wp + 4);
                    float4 h0 = *(const float4*)(hp);
                    float4 h1 = *(const float4*)(hp + 4);
                    float wv8[8] = {w0.x, w0.y, w0.z, w0.w, w1.x, w1.y, w1.z, w1.w};
                    float hv8[8] = {h0.x, h0.y, h0.z, h0.w, h1.x, h1.y, h1.z, h1.w};
                    float o[8];
                    #pragma unroll
                    for (int j = 0; j < 8; ++j) {
                        float r = ((float)ahi[mi][kq][j] + (float)alo[mi][kq][j]) - wv8[j];
                        o[j] = hv8[j] - r;
                    }
                    float* op = out + (size_t)row * DIM + ko;
                    *(float4*)(op)     = make_float4(o[0], o[1], o[2], o[3]);
                    *(float4*)(op + 4) = make_float4(o[4], o[5], o[6], o[7]);
                }
            }
        }
    }
}

extern "C" void kernel_launch(void* const* d_in, const int* in_sizes, int n_in,
                              void* d_out, int out_size, void* d_ws, size_t ws_size,
                              hipStream_t stream) {
    const float* h  = (const float*)d_in[0];
    const float* cb = (const float*)d_in[1];
    float* out = (float*)d_out;
    unsigned short* F = (unsigned short*)d_ws;
    float* wsq = (float*)((char*)d_ws + F_BYTES);

    hipFuncSetAttribute((const void*)rvq_main,
                        hipFuncAttributeMaxDynamicSharedMemorySize, SMEM_BYTES);

    rvq_wsq   <<<dim3(24),   dim3(256), 0, stream>>>(cb, wsq);
    rvq_repack<<<dim3(3072), dim3(64),  0, stream>>>(cb, F);
    rvq_main  <<<dim3(NROWS / 128), dim3(512), SMEM_BYTES, stream>>>(h, cb, F, wsq, out);
}